// Round 1
// baseline (282.240 us; speedup 1.0000x reference)
//
#include <hip/hip_runtime.h>

#define M2048 2048         // complex FFT length (real length 4096)
#define NSEG 511
#define NROWS 8            // rows 8..15 only
#define ROW0 8
#define TROW 16384         // samples per batch row
#define K0 21              // first needed freq bin
#define KEND 500           // bins k with 20 < k < 500
#define NFREQ 479
#define ACC_STRIDE 512     // padded per-row accumulator stride

// One block = one (signal, row, segment). Computes windowed 4096-pt real FFT
// via 2048-pt complex Stockham FFT, accumulates |X[k]|^2 for k in [21,500).
__global__ __launch_bounds__(256)
void psd_kernel(const float* __restrict__ pred,
                const float* __restrict__ target,
                float* __restrict__ acc) {
    __shared__ float2 buf[2][M2048];   // 32 KiB ping-pong

    const int bid = blockIdx.x;
    const int seg = bid % NSEG;
    const int row = (bid / NSEG) % NROWS + ROW0;
    const int sig = bid / (NSEG * NROWS);   // 0 = res (target-pred), 1 = target
    const int tid = threadIdx.x;

    // ---- load + window: sample t of the frame lives at batch row (2*seg + t/1024),
    // offset row*1024 + (t%1024). Window = 1 - cos(2*pi*t/4096) (hann*2).
    float* z_as_f = (float*)&buf[0][0];   // interleaved re/im == packed even/odd reals
    const float wstep = 6.28318530717958647692f / 4096.0f;
    #pragma unroll
    for (int it = 0; it < 16; ++it) {
        int t = tid + 256 * it;
        int b = 2 * seg + (t >> 10);
        int off = (row << 10) + (t & 1023);
        int addr = b * TROW + off;
        float v = target[addr];
        if (sig == 0) v -= pred[addr];
        float w = 1.0f - __cosf(wstep * (float)t);
        z_as_f[t] = v * w;   // z[m] = (x[2m], x[2m+1]) interleaved
    }
    __syncthreads();

    // ---- Stockham radix-2 DIF, 11 stages, self-sorting, ping-pong buffers.
    int n = M2048;
    int s = 1, ls = 0;
    #pragma unroll 1
    for (int stage = 0; stage < 11; ++stage) {
        const float2* __restrict__ x = buf[stage & 1];
        float2* __restrict__ y = buf[(stage + 1) & 1];
        const int m = n >> 1;
        const float theta0 = -6.28318530717958647692f / (float)n;
        #pragma unroll
        for (int r = 0; r < 4; ++r) {
            int tt = tid + 256 * r;        // 1024 butterflies/stage
            int q = tt & (s - 1);
            int p = tt >> ls;
            float sn, cs;
            __sincosf(theta0 * (float)p, &sn, &cs);   // wp = e^{-2*pi*i*p/n} = (cs, sn)
            float2 a = x[q + s * p];
            float2 b = x[q + s * (p + m)];
            float2 su = make_float2(a.x + b.x, a.y + b.y);
            float dx = a.x - b.x, dy = a.y - b.y;
            float2 tw = make_float2(dx * cs - dy * sn, dx * sn + dy * cs);
            y[q + s * 2 * p] = su;
            y[q + s * 2 * p + s] = tw;
        }
        n = m; s <<= 1; ++ls;
        __syncthreads();
    }
    // result in buf[1], natural order: Z[k] = FFT_2048(even + i*odd)

    // ---- untangle real FFT + power + accumulate (only bins 21..499)
    const float2* __restrict__ Z = buf[1];
    #pragma unroll
    for (int r = 0; r < 2; ++r) {
        int k = K0 + tid + 256 * r;
        if (k < KEND) {
            float2 zk = Z[k];
            float2 zn = Z[M2048 - k];
            // E = (Z[k] + conj(Z[M-k]))/2 ; O = (Z[k] - conj(Z[M-k]))/(2i)
            float Ex = 0.5f * (zk.x + zn.x);
            float Ey = 0.5f * (zk.y - zn.y);
            float dx = zk.x - zn.x;
            float dy = zk.y + zn.y;
            float Ox = 0.5f * dy;
            float Oy = -0.5f * dx;
            float sn, cs;
            __sincosf(-6.28318530717958647692f * (float)k / 4096.0f, &sn, &cs);
            float xr = Ex + Ox * cs - Oy * sn;
            float xi = Ey + Ox * sn + Oy * cs;
            float pw = xr * xr + xi * xi;
            atomicAdd(&acc[(sig * NROWS + (row - ROW0)) * ACC_STRIDE + (k - K0)], pw);
        }
    }
}

// Single block: out = sum over (row,k) of P_res/P_tgt, / 240.
// (dfreq=1, scale=480, mean(last 8)*16 => factor 2/480 = 1/240; /T cancels in ratio)
__global__ __launch_bounds__(256)
void reduce_kernel(const float* __restrict__ acc, float* __restrict__ out) {
    __shared__ float sh[256];
    int tid = threadIdx.x;
    float sum = 0.0f;
    for (int n = tid; n < NROWS * NFREQ; n += 256) {
        int r = n / NFREQ;
        int k = n % NFREQ;
        float num = acc[r * ACC_STRIDE + k];
        float den = acc[(NROWS + r) * ACC_STRIDE + k];
        sum += num / den;
    }
    sh[tid] = sum;
    __syncthreads();
    for (int s = 128; s > 0; s >>= 1) {
        if (tid < s) sh[tid] += sh[tid + s];
        __syncthreads();
    }
    if (tid == 0) out[0] = sh[0] * (1.0f / 240.0f);
}

extern "C" void kernel_launch(void* const* d_in, const int* in_sizes, int n_in,
                              void* d_out, int out_size, void* d_ws, size_t ws_size,
                              hipStream_t stream) {
    const float* pred = (const float*)d_in[0];
    const float* target = (const float*)d_in[1];
    float* acc = (float*)d_ws;   // [2][NROWS][ACC_STRIDE] floats = 32 KiB

    hipMemsetAsync(acc, 0, 2 * NROWS * ACC_STRIDE * sizeof(float), stream);
    psd_kernel<<<2 * NROWS * NSEG, 256, 0, stream>>>(pred, target, acc);
    reduce_kernel<<<1, 256, 0, stream>>>(acc, (float*)d_out);
}

// Round 2
// 199.802 us; speedup vs baseline: 1.4126x; 1.4126x over previous
//
#include <hip/hip_runtime.h>

#define NSEG 511
#define NROWS 8            // rows 8..15 only
#define ROW0 8
#define K0 21              // first needed freq bin
#define KEND 500           // bins k with 20 < k < 500
#define NFREQ 479
#define ACC_STRIDE 512     // padded per-row accumulator stride

// Position of bin k after in-place DIF with stage radices [4,4,4,4,4,2]
// (digit-reversed order: pos = k0*512 + k1*128 + k2*32 + k3*8 + k4*2 + k5,
//  k0..k4 base-4 digits of k from LSB, k5 the final bit)
__device__ __forceinline__ int dr_pos(int k) {
    int p = k & 3;
    p = (p << 2) | ((k >> 2) & 3);
    p = (p << 2) | ((k >> 4) & 3);
    p = (p << 2) | ((k >> 6) & 3);
    p = (p << 2) | ((k >> 8) & 3);
    p = (p << 1) | ((k >> 10) & 1);
    return p;
}

__device__ __forceinline__ float2 cmul(float2 a, float2 b) {
    return make_float2(a.x * b.x - a.y * b.y, a.x * b.y + a.y * b.x);
}

// One block = one (signal, row, segment). Windowed 4096-pt real FFT via
// in-place 2048-pt complex radix-4 DIF FFT (digit-reversed output),
// accumulates |X[k]|^2 for k in [21,500).
__global__ __launch_bounds__(256)
void psd_kernel(const float* __restrict__ pred,
                const float* __restrict__ target,
                float* __restrict__ acc) {
    __shared__ float2 buf[2048];   // 16 KiB, in-place

    const int bid = blockIdx.x;
    const int seg = bid % NSEG;
    const int row = (bid / NSEG) % NROWS + ROW0;
    const int sig = bid / (NSEG * NROWS);   // 0 = res (target-pred), 1 = target
    const int tid = threadIdx.x;

    // ---- load + window (float4 global loads, b128 LDS stores).
    // Sample t of the frame lives at batch row (2*seg + t/1024), offset
    // row*1024 + (t%1024). Window = 1 - cos(2*pi*t/4096) (hann*2).
    // Interleaved packing: z[m] = (x[2m], x[2m+1]).
    const float4* tgt4 = (const float4*)target;
    const float4* prd4 = (const float4*)pred;
    float4* b4 = (float4*)buf;
    const float wstep = 6.28318530717958647692f / 4096.0f;
    #pragma unroll
    for (int it = 0; it < 4; ++it) {
        int t4 = tid + 256 * it;              // float4 index within frame
        int b  = 2 * seg + (t4 >> 8);
        int g  = b * 4096 + (row << 8) + (t4 & 255);
        float4 v = tgt4[g];
        if (sig == 0) {
            float4 p = prd4[g];
            v.x -= p.x; v.y -= p.y; v.z -= p.z; v.w -= p.w;
        }
        float t0 = (float)(4 * t4);
        float w0 = 1.0f - __cosf(wstep * t0);
        float w1 = 1.0f - __cosf(wstep * (t0 + 1.0f));
        float w2 = 1.0f - __cosf(wstep * (t0 + 2.0f));
        float w3 = 1.0f - __cosf(wstep * (t0 + 3.0f));
        b4[t4] = make_float4(v.x * w0, v.y * w1, v.z * w2, v.w * w3);
    }
    __syncthreads();

    // ---- 5 in-place DIF radix-4 stages: n = 2048, 512, 128, 32, 8.
    // Butterfly (i, i+n/4, i+n/2, i+3n/4) is read+written by one thread ->
    // single barrier per stage, no ping-pong.
    #pragma unroll
    for (int st = 0; st < 5; ++st) {
        const int lnb = 9 - 2 * st;           // log2(butterflies per block)
        const int nb  = 1 << lnb;
        const int q   = nb;                   // n/4
        const float theta = -6.28318530717958647692f / (float)(nb << 2);
        #pragma unroll
        for (int u = 0; u < 2; ++u) {
            int t = tid + 256 * u;            // 512 butterflies per stage
            int j = t & (nb - 1);
            int base = ((t >> lnb) << (lnb + 2)) + j;
            float2 x0 = buf[base];
            float2 x1 = buf[base + q];
            float2 x2 = buf[base + 2 * q];
            float2 x3 = buf[base + 3 * q];
            float2 s0 = make_float2(x0.x + x2.x, x0.y + x2.y);
            float2 d0 = make_float2(x0.x - x2.x, x0.y - x2.y);
            float2 s1 = make_float2(x1.x + x3.x, x1.y + x3.y);
            float2 d1 = make_float2(x1.x - x3.x, x1.y - x3.y);
            float2 c0 = make_float2(s0.x + s1.x, s0.y + s1.y);
            float2 c2 = make_float2(s0.x - s1.x, s0.y - s1.y);
            float2 c1 = make_float2(d0.x + d1.y, d0.y - d1.x);   // d0 - i*d1
            float2 c3 = make_float2(d0.x - d1.y, d0.y + d1.x);   // d0 + i*d1
            float sn, cs;
            __sincosf(theta * (float)j, &sn, &cs);
            float2 w1 = make_float2(cs, sn);
            float2 w2 = make_float2(cs * cs - sn * sn, 2.0f * cs * sn);
            float2 w3 = cmul(w2, w1);
            buf[base]         = c0;
            buf[base + q]     = cmul(c1, w1);
            buf[base + 2 * q] = cmul(c2, w2);
            buf[base + 3 * q] = cmul(c3, w3);
        }
        __syncthreads();
    }

    // ---- final radix-2 stage (n=2): pairs (2t, 2t+1), twiddle-free,
    // done as in-place float4 (conflict-free b128).
    #pragma unroll
    for (int u = 0; u < 4; ++u) {
        int t = tid + 256 * u;
        float4 v = b4[t];
        b4[t] = make_float4(v.x + v.z, v.y + v.w, v.x - v.z, v.y - v.w);
    }
    __syncthreads();

    // ---- untangle real FFT + power + accumulate (bins 21..499).
    // Z[k] lives at buf[dr_pos(k)] (digit-reversed order).
    #pragma unroll
    for (int rr = 0; rr < 2; ++rr) {
        int k = K0 + tid + 256 * rr;
        if (k < KEND) {
            float2 zk = buf[dr_pos(k)];
            float2 zn = buf[dr_pos(2048 - k)];
            // E = (Z[k] + conj(Z[M-k]))/2 ; O = (Z[k] - conj(Z[M-k]))/(2i)
            float Ex = 0.5f * (zk.x + zn.x);
            float Ey = 0.5f * (zk.y - zn.y);
            float Ox = 0.5f * (zk.y + zn.y);
            float Oy = -0.5f * (zk.x - zn.x);
            float sn, cs;
            __sincosf(-6.28318530717958647692f * (float)k / 4096.0f, &sn, &cs);
            float xr = Ex + Ox * cs - Oy * sn;
            float xi = Ey + Ox * sn + Oy * cs;
            float pw = xr * xr + xi * xi;
            atomicAdd(&acc[(sig * NROWS + (row - ROW0)) * ACC_STRIDE + (k - K0)], pw);
        }
    }
}

// Single block: out = sum over (row,k) of P_res/P_tgt, / 240.
// (dfreq=1, scale=480, mean(last 8)*16 => factor 2/480 = 1/240; /T cancels)
__global__ __launch_bounds__(256)
void reduce_kernel(const float* __restrict__ acc, float* __restrict__ out) {
    __shared__ float sh[256];
    int tid = threadIdx.x;
    float sum = 0.0f;
    for (int n = tid; n < NROWS * NFREQ; n += 256) {
        int r = n / NFREQ;
        int k = n % NFREQ;
        sum += acc[r * ACC_STRIDE + k] / acc[(NROWS + r) * ACC_STRIDE + k];
    }
    sh[tid] = sum;
    __syncthreads();
    for (int s = 128; s > 0; s >>= 1) {
        if (tid < s) sh[tid] += sh[tid + s];
        __syncthreads();
    }
    if (tid == 0) out[0] = sh[0] * (1.0f / 240.0f);
}

extern "C" void kernel_launch(void* const* d_in, const int* in_sizes, int n_in,
                              void* d_out, int out_size, void* d_ws, size_t ws_size,
                              hipStream_t stream) {
    const float* pred = (const float*)d_in[0];
    const float* target = (const float*)d_in[1];
    float* acc = (float*)d_ws;   // [2][NROWS][ACC_STRIDE] floats = 32 KiB

    hipMemsetAsync(acc, 0, 2 * NROWS * ACC_STRIDE * sizeof(float), stream);
    psd_kernel<<<2 * NROWS * NSEG, 256, 0, stream>>>(pred, target, acc);
    reduce_kernel<<<1, 256, 0, stream>>>(acc, (float*)d_out);
}